// Round 3
// baseline (127.429 us; speedup 1.0000x reference)
//
#include <hip/hip_runtime.h>

#define VOCAB 50257
#define EMBD  300
#define EMBP  320      // EMB padded to multiple of 32 for MFMA K
#define HID   1024
#define B3H   3072
#define BATCH 128
#define NBLK3 786      // ceil(50257/64)
#define BK    64       // k3 K-tile
#define NT3   16       // 1024/64 tiles

typedef __attribute__((ext_vector_type(8))) short short8;
typedef __attribute__((ext_vector_type(4))) float f32x4;
typedef unsigned short ushort_t;

__device__ __forceinline__ unsigned short f2bf(float f) {
  unsigned int u = __float_as_uint(f);
  u += 0x7fffu + ((u >> 16) & 1u);
  return (unsigned short)(u >> 16);
}

__device__ __forceinline__ void gload16(const void* g, void* l) {
  __builtin_amdgcn_global_load_lds(
      (const __attribute__((address_space(1))) void*)g,
      (__attribute__((address_space(3))) void*)l, 16, 0, 0);
}

#define MEMF() asm volatile("" ::: "memory")

// ---------------- K0: gather + bf16 casts (x, h, w_ih, w_hh) ----------------
// regions: NX scalar, NH scalar, NWI scalar, NWH vectorized x8
__global__ __launch_bounds__(256) void k0_prep(
    const int* __restrict__ ids, const float* __restrict__ emb,
    const float* __restrict__ hprev, const float* __restrict__ wih,
    const float* __restrict__ whh,
    ushort_t* __restrict__ xbf, ushort_t* __restrict__ hbf,
    ushort_t* __restrict__ wihbf, ushort_t* __restrict__ whhbf) {
  const int NX  = BATCH * EMBP;        // 40960
  const int NH  = BATCH * HID;         // 131072
  const int NWI = B3H * EMBP;          // 983040
  // NWH/8 = 393216 ; total threads = 1548288 = 6048*256
  int i = blockIdx.x * 256 + threadIdx.x;
  if (i < NX) {
    int b = i / EMBP, k = i - b * EMBP;
    float f = (k < EMBD) ? emb[(size_t)ids[b] * EMBD + k] : 0.f;
    xbf[i] = f2bf(f);
  } else if (i < NX + NH) {
    int j = i - NX;
    hbf[j] = f2bf(hprev[j]);
  } else if (i < NX + NH + NWI) {
    int j = i - NX - NH;
    int n = j / EMBP, k = j - n * EMBP;
    wihbf[j] = f2bf((k < EMBD) ? wih[(size_t)n * EMBD + k] : 0.f);
  } else {
    int j = (i - NX - NH - NWI) * 8;
    f32x4 a = *(const f32x4*)(whh + j);
    f32x4 b = *(const f32x4*)(whh + j + 4);
    short8 o;
    o[0] = (short)f2bf(a[0]); o[1] = (short)f2bf(a[1]);
    o[2] = (short)f2bf(a[2]); o[3] = (short)f2bf(a[3]);
    o[4] = (short)f2bf(b[0]); o[5] = (short)f2bf(b[1]);
    o[6] = (short)f2bf(b[2]); o[7] = (short)f2bf(b[3]);
    *(short8*)(whhbf + j) = o;
  }
}

// ---------------- K1: gates GEMMs, 1 wave per block, 16 cols, bf16 B ----------------
// grid (192, 2): y=0 -> gi = x @ w_ih^T (K=320), y=1 -> gh = h @ w_hh^T (K=1024)
__global__ __launch_bounds__(64) void k1_gemm_gates(
    const ushort_t* __restrict__ xbf, const ushort_t* __restrict__ hbf,
    const ushort_t* __restrict__ wihbf, const ushort_t* __restrict__ whhbf,
    float* __restrict__ gi, float* __restrict__ gh) {
  const bool is_h = (blockIdx.y == 1);
  const ushort_t* A = is_h ? hbf : xbf;
  const ushort_t* B = is_h ? whhbf : wihbf;
  const int K = is_h ? HID : EMBP;
  const int lane = threadIdx.x;
  const int r = lane & 15, g = lane >> 4;
  const int n = blockIdx.x * 16 + r;
  const ushort_t* brow = B + (size_t)n * K;

  f32x4 acc[8];
#pragma unroll
  for (int i = 0; i < 8; i++) acc[i] = (f32x4){0.f, 0.f, 0.f, 0.f};

#pragma unroll 2
  for (int k0 = 0; k0 < K; k0 += 32) {
    short8 bfr = *(const short8*)(brow + k0 + g * 8);
#pragma unroll
    for (int mi = 0; mi < 8; mi++) {
      short8 afr = *(const short8*)(A + (size_t)(mi * 16 + r) * K + k0 + g * 8);
      acc[mi] = __builtin_amdgcn_mfma_f32_16x16x32_bf16(afr, bfr, acc[mi], 0, 0, 0);
    }
  }
  float* C = is_h ? gh : gi;
#pragma unroll
  for (int mi = 0; mi < 8; mi++)
#pragma unroll
    for (int rr = 0; rr < 4; rr++)
      C[(size_t)(mi * 16 + g * 4 + rr) * B3H + n] = acc[mi][rr];
}

// ---------------- K2: elementwise GRU gates -> h_new ----------------
__global__ __launch_bounds__(256) void k2_gates(
    const float* __restrict__ gi, const float* __restrict__ gh,
    const float* __restrict__ bih, const float* __restrict__ bhh,
    const float* __restrict__ hprev,
    float* __restrict__ hnew_out, ushort_t* __restrict__ hnbf) {
  int i = blockIdx.x * 256 + threadIdx.x;     // 0..131071
  int b = i >> 10, j = i & 1023;
  size_t base = (size_t)b * B3H;
  float ir = gi[base + j]          + bih[j];
  float iz = gi[base + HID + j]    + bih[HID + j];
  float in_ = gi[base + 2*HID + j] + bih[2*HID + j];
  float hr = gh[base + j]          + bhh[j];
  float hz = gh[base + HID + j]    + bhh[HID + j];
  float hn = gh[base + 2*HID + j]  + bhh[2*HID + j];
  float rg = 1.f / (1.f + expf(-(ir + hr)));
  float zg = 1.f / (1.f + expf(-(iz + hz)));
  float ng = tanhf(in_ + rg * hn);
  float h  = hprev[i];
  float hnew = (1.f - zg) * ng + zg * h;
  hnew_out[i] = hnew;
  hnbf[i] = f2bf(hnew);
}

// ---------------- K3: logits GEMM ----------------
// W per-lane in registers, 3-slot pipeline (depth 2, BK=64).
// A staged via global_load_lds into 3-buffer LDS ring, XOR-swizzled 16B chunks.
// One barrier + one counted s_waitcnt per tile; 8 VMEM issues per iteration.
__global__ __launch_bounds__(256, 3) void k3_logits(
    const ushort_t* __restrict__ Abf, const float* __restrict__ Wout,
    const float* __restrict__ bout, float* __restrict__ out,
    float2* __restrict__ part) {
  __shared__ ushort_t At[3][128 * BK];   // 48 KB

  const int lane = threadIdx.x & 63;
  const int wid  = threadIdx.x >> 6;
  const int r = lane & 15, g = lane >> 4;
  const int vb = blockIdx.x * 64;
  int wv = vb + wid * 16 + r; if (wv > VOCAB - 1) wv = VOCAB - 1;
  const float* wrow = Wout + (size_t)wv * HID;

  // A staging: lane covers row base+(lane>>3), swizzled 16B chunk (lane&7)^(lane>>3)
  const int arow = lane >> 3;              // 0..7
  const int achk = (lane & 7) ^ arow;      // 0..7

  f32x4 acc[8];
#pragma unroll
  for (int i = 0; i < 8; i++) acc[i] = (f32x4){0.f, 0.f, 0.f, 0.f};

  f32x4 wp[3][4];

#define WISSUE(T, S)                                                     \
  {                                                                      \
    wp[S][0] = *(const f32x4*)(wrow + (T) * BK + g * 8);                 \
    wp[S][1] = *(const f32x4*)(wrow + (T) * BK + g * 8 + 4);             \
    wp[S][2] = *(const f32x4*)(wrow + (T) * BK + 32 + g * 8);            \
    wp[S][3] = *(const f32x4*)(wrow + (T) * BK + 32 + g * 8 + 4);        \
  }

#define AISSUE(T, S)                                                     \
  {                                                                      \
    _Pragma("unroll")                                                    \
    for (int i = 0; i < 4; ++i) {                                        \
      int rowbase = wid * 32 + i * 8;                                    \
      gload16(Abf + (size_t)(rowbase + arow) * HID + (T) * BK + achk * 8,\
              &At[S][rowbase * BK]);                                     \
    }                                                                    \
  }

  MEMF(); WISSUE(0, 0); MEMF(); AISSUE(0, 0); MEMF();
  WISSUE(1, 1); MEMF(); AISSUE(1, 1); MEMF();

#pragma unroll
  for (int t = 0; t < NT3; ++t) {
    const int s = t % 3;
    if (t + 1 < NT3) { asm volatile("s_waitcnt vmcnt(8) lgkmcnt(0)" ::: "memory"); }
    else             { asm volatile("s_waitcnt vmcnt(0) lgkmcnt(0)" ::: "memory"); }
    __builtin_amdgcn_s_barrier(); MEMF();
    if (t + 2 < NT3) {
      WISSUE(t + 2, (t + 2) % 3); MEMF();
      AISSUE(t + 2, (t + 2) % 3); MEMF();
    }
    // convert W slot s -> two bf16 fragments (k-halves of the 64-k tile)
    short8 b0, b1;
    b0[0] = (short)f2bf(wp[s][0][0]); b0[1] = (short)f2bf(wp[s][0][1]);
    b0[2] = (short)f2bf(wp[s][0][2]); b0[3] = (short)f2bf(wp[s][0][3]);
    b0[4] = (short)f2bf(wp[s][1][0]); b0[5] = (short)f2bf(wp[s][1][1]);
    b0[6] = (short)f2bf(wp[s][1][2]); b0[7] = (short)f2bf(wp[s][1][3]);
    b1[0] = (short)f2bf(wp[s][2][0]); b1[1] = (short)f2bf(wp[s][2][1]);
    b1[2] = (short)f2bf(wp[s][2][2]); b1[3] = (short)f2bf(wp[s][2][3]);
    b1[4] = (short)f2bf(wp[s][3][0]); b1[5] = (short)f2bf(wp[s][3][1]);
    b1[6] = (short)f2bf(wp[s][3][2]); b1[7] = (short)f2bf(wp[s][3][3]);
    const int sw = r & 7;
#pragma unroll
    for (int mi = 0; mi < 8; ++mi) {
      short8 a0 = *(const short8*)&At[s][(mi * 16 + r) * BK + ((g ^ sw) * 8)];
      acc[mi] = __builtin_amdgcn_mfma_f32_16x16x32_bf16(a0, b0, acc[mi], 0, 0, 0);
    }
#pragma unroll
    for (int mi = 0; mi < 8; ++mi) {
      short8 a1 = *(const short8*)&At[s][(mi * 16 + r) * BK + (((4 + g) ^ sw) * 8)];
      acc[mi] = __builtin_amdgcn_mfma_f32_16x16x32_bf16(a1, b1, acc[mi], 0, 0, 0);
    }
    MEMF();
  }
#undef WISSUE
#undef AISSUE

  // ---- epilogue: bias, store logits, wave-parallel softmax partials ----
  const int v = vb + wid * 16 + r;
  const bool vok = (v < VOCAB);
  float bias = bout[vok ? v : VOCAB - 1];
#pragma unroll
  for (int mi = 0; mi < 8; ++mi) {
#pragma unroll
    for (int rr = 0; rr < 4; ++rr) {
      float val = acc[mi][rr] + bias;
      int b = mi * 16 + g * 4 + rr;
      if (vok) out[(size_t)b * VOCAB + v] = val;
      float sv = vok ? val : -INFINITY;
      float m = sv;
      m = fmaxf(m, __shfl_xor(m, 1));
      m = fmaxf(m, __shfl_xor(m, 2));
      m = fmaxf(m, __shfl_xor(m, 4));
      m = fmaxf(m, __shfl_xor(m, 8));
      float ss = vok ? __expf(sv - m) : 0.f;
      ss += __shfl_xor(ss, 1);
      ss += __shfl_xor(ss, 2);
      ss += __shfl_xor(ss, 4);
      ss += __shfl_xor(ss, 8);
      if (r == 0) part[((size_t)blockIdx.x * 4 + wid) * 128 + b] = make_float2(m, ss);
    }
  }
}

// ---------------- K4: combine per-wave partials -> stat[b] ----------------
__global__ __launch_bounds__(256) void k4_combine(
    const float2* __restrict__ part, float* __restrict__ stat) {
  const int NP = NBLK3 * 4;   // 3144
  int b = blockIdx.x, t = threadIdx.x;
  float m = -INFINITY;
  for (int i = t; i < NP; i += 256) m = fmaxf(m, part[(size_t)i * 128 + b].x);
  __shared__ float red[256];
  red[t] = m; __syncthreads();
  for (int s = 128; s > 0; s >>= 1) {
    if (t < s) red[t] = fmaxf(red[t], red[t + s]);
    __syncthreads();
  }
  float M = red[0]; __syncthreads();
  float ssum = 0.f;
  for (int i = t; i < NP; i += 256) {
    float2 p = part[(size_t)i * 128 + b];
    ssum += p.y * __expf(p.x - M);
  }
  red[t] = ssum; __syncthreads();
  for (int s = 128; s > 0; s >>= 1) {
    if (t < s) red[t] += red[t + s];
    __syncthreads();
  }
  if (t == 0) stat[b] = M + logf(red[0]);
}

// ---------------- K5: out = logit - stat[b], float4 ----------------
__global__ __launch_bounds__(256) void k5_final(
    float* __restrict__ out, const float* __restrict__ stat) {
  const int total = BATCH * VOCAB;        // 6432896, divisible by 4
  int i4 = blockIdx.x * 256 + threadIdx.x;
  int base = i4 * 4;
  if (base >= total) return;
  float4 v = *(float4*)(out + base);
  int b0 = base / VOCAB, b3 = (base + 3) / VOCAB;
  if (b0 == b3) {
    float s = stat[b0];
    v.x -= s; v.y -= s; v.z -= s; v.w -= s;
  } else {
    v.x -= stat[base / VOCAB];
    v.y -= stat[(base + 1) / VOCAB];
    v.z -= stat[(base + 2) / VOCAB];
    v.w -= stat[(base + 3) / VOCAB];
  }
  *(float4*)(out + base) = v;
}

extern "C" void kernel_launch(void* const* d_in, const int* in_sizes, int n_in,
                              void* d_out, int out_size, void* d_ws, size_t ws_size,
                              hipStream_t stream) {
  const int*   ids   = (const int*)  d_in[0];
  const float* hprev = (const float*)d_in[1];
  // d_in[2] = encoder_output, unused by the reference
  const float* emb   = (const float*)d_in[3];
  const float* wih   = (const float*)d_in[4];
  const float* whh   = (const float*)d_in[5];
  const float* bih   = (const float*)d_in[6];
  const float* bhh   = (const float*)d_in[7];
  const float* Wout  = (const float*)d_in[8];
  const float* bout  = (const float*)d_in[9];
  float* out = (float*)d_out;
  char* ws = (char*)d_ws;

  // ws layout (bytes); max end ~12.01 MB. part/stat alias dead whhbf region.
  ushort_t* xbf   = (ushort_t*)(ws + 0);         // 128x320 bf16
  ushort_t* hbf   = (ushort_t*)(ws + 81920);     // 128x1024 bf16
  ushort_t* wihbf = (ushort_t*)(ws + 344064);    // 3072x320 bf16
  ushort_t* whhbf = (ushort_t*)(ws + 2310144);   // 3072x1024 bf16 (dead after k1)
  float*    gi    = (float*)(ws + 8601600);      // 128x3072 f32
  float*    gh    = (float*)(ws + 10174464);     // 128x3072 f32
  ushort_t* hnbf  = (ushort_t*)(ws + 11747328);  // 128x1024 bf16
  float2*   part  = (float2*)(ws + 2310144);     // 3144x128 float2 (aliases whhbf)
  float*    stat  = (float*)(ws + 5529600);      // 128 f32

  float* hnew_out = out + (size_t)BATCH * VOCAB;

  hipLaunchKernelGGL(k0_prep, dim3(6048), dim3(256), 0, stream,
                     ids, emb, hprev, wih, whh, xbf, hbf, wihbf, whhbf);
  hipLaunchKernelGGL(k1_gemm_gates, dim3(192, 2), dim3(64), 0, stream,
                     xbf, hbf, wihbf, whhbf, gi, gh);
  hipLaunchKernelGGL(k2_gates, dim3(512), dim3(256), 0, stream,
                     gi, gh, bih, bhh, hprev, hnew_out, hnbf);
  hipLaunchKernelGGL(k3_logits, dim3(NBLK3), dim3(256), 0, stream,
                     hnbf, Wout, bout, out, part);
  hipLaunchKernelGGL(k4_combine, dim3(128), dim3(256), 0, stream, part, stat);
  hipLaunchKernelGGL(k5_final, dim3((BATCH * VOCAB / 4 + 255) / 256), dim3(256), 0, stream,
                     out, stat);
}

// Round 4
// 124.166 us; speedup vs baseline: 1.0263x; 1.0263x over previous
//
#include <hip/hip_runtime.h>

#define VOCAB 50257
#define EMBD  300
#define EMBP  320      // EMB padded to multiple of 32 for MFMA K
#define HID   1024
#define B3H   3072
#define BATCH 128
#define NBLK3 786      // ceil(50257/64)
#define BK    64       // k3 K-tile
#define NT3   16       // 1024/64 tiles

typedef __attribute__((ext_vector_type(8))) short short8;
typedef __attribute__((ext_vector_type(4))) float f32x4;
typedef unsigned short ushort_t;

__device__ __forceinline__ unsigned short f2bf(float f) {
  unsigned int u = __float_as_uint(f);
  u += 0x7fffu + ((u >> 16) & 1u);
  return (unsigned short)(u >> 16);
}

__device__ __forceinline__ void gload16(const void* g, void* l) {
  __builtin_amdgcn_global_load_lds(
      (const __attribute__((address_space(1))) void*)g,
      (__attribute__((address_space(3))) void*)l, 16, 0, 0);
}

#define MEMF() asm volatile("" ::: "memory")

// ---------------- K0: gather + bf16 casts (x, h, w_ih, w_hh) ----------------
__global__ __launch_bounds__(256) void k0_prep(
    const int* __restrict__ ids, const float* __restrict__ emb,
    const float* __restrict__ hprev, const float* __restrict__ wih,
    const float* __restrict__ whh,
    ushort_t* __restrict__ xbf, ushort_t* __restrict__ hbf,
    ushort_t* __restrict__ wihbf, ushort_t* __restrict__ whhbf) {
  const int NX  = BATCH * EMBP;        // 40960
  const int NH  = BATCH * HID;         // 131072
  const int NWI = B3H * EMBP;          // 983040
  // NWH/8 = 393216 ; total threads = 1548288 = 6048*256
  int i = blockIdx.x * 256 + threadIdx.x;
  if (i < NX) {
    int b = i / EMBP, k = i - b * EMBP;
    float f = (k < EMBD) ? emb[(size_t)ids[b] * EMBD + k] : 0.f;
    xbf[i] = f2bf(f);
  } else if (i < NX + NH) {
    int j = i - NX;
    hbf[j] = f2bf(hprev[j]);
  } else if (i < NX + NH + NWI) {
    int j = i - NX - NH;
    int n = j / EMBP, k = j - n * EMBP;
    wihbf[j] = f2bf((k < EMBD) ? wih[(size_t)n * EMBD + k] : 0.f);
  } else {
    int j = (i - NX - NH - NWI) * 8;
    f32x4 a = *(const f32x4*)(whh + j);
    f32x4 b = *(const f32x4*)(whh + j + 4);
    short8 o;
    o[0] = (short)f2bf(a[0]); o[1] = (short)f2bf(a[1]);
    o[2] = (short)f2bf(a[2]); o[3] = (short)f2bf(a[3]);
    o[4] = (short)f2bf(b[0]); o[5] = (short)f2bf(b[1]);
    o[6] = (short)f2bf(b[2]); o[7] = (short)f2bf(b[3]);
    *(short8*)(whhbf + j) = o;
  }
}

// ---------------- K1: gates GEMMs, 1 wave per block, 16 cols, bf16 B ----------------
__global__ __launch_bounds__(64) void k1_gemm_gates(
    const ushort_t* __restrict__ xbf, const ushort_t* __restrict__ hbf,
    const ushort_t* __restrict__ wihbf, const ushort_t* __restrict__ whhbf,
    float* __restrict__ gi, float* __restrict__ gh) {
  const bool is_h = (blockIdx.y == 1);
  const ushort_t* A = is_h ? hbf : xbf;
  const ushort_t* B = is_h ? whhbf : wihbf;
  const int K = is_h ? HID : EMBP;
  const int lane = threadIdx.x;
  const int r = lane & 15, g = lane >> 4;
  const int n = blockIdx.x * 16 + r;
  const ushort_t* brow = B + (size_t)n * K;

  f32x4 acc[8];
#pragma unroll
  for (int i = 0; i < 8; i++) acc[i] = (f32x4){0.f, 0.f, 0.f, 0.f};

#pragma unroll 2
  for (int k0 = 0; k0 < K; k0 += 32) {
    short8 bfr = *(const short8*)(brow + k0 + g * 8);
#pragma unroll
    for (int mi = 0; mi < 8; mi++) {
      short8 afr = *(const short8*)(A + (size_t)(mi * 16 + r) * K + k0 + g * 8);
      acc[mi] = __builtin_amdgcn_mfma_f32_16x16x32_bf16(afr, bfr, acc[mi], 0, 0, 0);
    }
  }
  float* C = is_h ? gh : gi;
#pragma unroll
  for (int mi = 0; mi < 8; mi++)
#pragma unroll
    for (int rr = 0; rr < 4; rr++)
      C[(size_t)(mi * 16 + g * 4 + rr) * B3H + n] = acc[mi][rr];
}

// ---------------- K2: elementwise GRU gates -> h_new ----------------
__global__ __launch_bounds__(256) void k2_gates(
    const float* __restrict__ gi, const float* __restrict__ gh,
    const float* __restrict__ bih, const float* __restrict__ bhh,
    const float* __restrict__ hprev,
    float* __restrict__ hnew_out, ushort_t* __restrict__ hnbf) {
  int i = blockIdx.x * 256 + threadIdx.x;     // 0..131071
  int b = i >> 10, j = i & 1023;
  size_t base = (size_t)b * B3H;
  float ir = gi[base + j]          + bih[j];
  float iz = gi[base + HID + j]    + bih[HID + j];
  float in_ = gi[base + 2*HID + j] + bih[2*HID + j];
  float hr = gh[base + j]          + bhh[j];
  float hz = gh[base + HID + j]    + bhh[HID + j];
  float hn = gh[base + 2*HID + j]  + bhh[2*HID + j];
  float rg = 1.f / (1.f + expf(-(ir + hr)));
  float zg = 1.f / (1.f + expf(-(iz + hz)));
  float ng = tanhf(in_ + rg * hn);
  float h  = hprev[i];
  float hnew = (1.f - zg) * ng + zg * h;
  hnew_out[i] = hnew;
  hnbf[i] = f2bf(hnew);
}

// ---------------- K3: logits GEMM ----------------
// Hand-unrolled 16-step pipeline, depth 2. W in named register sets wp0/wp1/wp2
// (all indices compile-time literals -> guaranteed register residency, rule #20).
// A staged via global_load_lds into 3-buffer LDS ring, XOR-swizzled chunks.
// One barrier + one counted vmcnt per tile; 8 VMEM issues per tile.
__global__ __launch_bounds__(256, 3) void k3_logits(
    const ushort_t* __restrict__ Abf, const float* __restrict__ Wout,
    const float* __restrict__ bout, float* __restrict__ out,
    float2* __restrict__ part) {
  __shared__ ushort_t At[3][128 * BK];   // 48 KB

  const int lane = threadIdx.x & 63;
  const int wid  = threadIdx.x >> 6;
  const int r = lane & 15, g = lane >> 4;
  const int vb = blockIdx.x * 64;
  int wv = vb + wid * 16 + r; if (wv > VOCAB - 1) wv = VOCAB - 1;
  const float* wrow = Wout + (size_t)wv * HID;

  // A staging: lane covers row base+(lane>>3), swizzled 16B chunk (lane&7)^(lane>>3)
  const int arow = lane >> 3;              // 0..7
  const int achk = (lane & 7) ^ arow;      // 0..7

  f32x4 acc[8];
#pragma unroll
  for (int i = 0; i < 8; i++) acc[i] = (f32x4){0.f, 0.f, 0.f, 0.f};

  f32x4 wp0[4], wp1[4], wp2[4];
  const int sw = r & 7;

#define WISSUE(T, WP)                                                    \
  {                                                                      \
    WP[0] = *(const f32x4*)(wrow + (T) * BK + g * 8);                    \
    WP[1] = *(const f32x4*)(wrow + (T) * BK + g * 8 + 4);                \
    WP[2] = *(const f32x4*)(wrow + (T) * BK + 32 + g * 8);               \
    WP[3] = *(const f32x4*)(wrow + (T) * BK + 32 + g * 8 + 4);           \
  }

#define AISSUE(T, S)                                                     \
  {                                                                      \
    _Pragma("unroll")                                                    \
    for (int i = 0; i < 4; ++i) {                                        \
      int rowbase = wid * 32 + i * 8;                                    \
      gload16(Abf + (size_t)(rowbase + arow) * HID + (T) * BK + achk * 8,\
              &At[S][rowbase * BK]);                                     \
    }                                                                    \
  }

#define COMPUTE(WP, S)                                                   \
  {                                                                      \
    short8 b0, b1;                                                       \
    b0[0] = (short)f2bf(WP[0][0]); b0[1] = (short)f2bf(WP[0][1]);        \
    b0[2] = (short)f2bf(WP[0][2]); b0[3] = (short)f2bf(WP[0][3]);        \
    b0[4] = (short)f2bf(WP[1][0]); b0[5] = (short)f2bf(WP[1][1]);        \
    b0[6] = (short)f2bf(WP[1][2]); b0[7] = (short)f2bf(WP[1][3]);        \
    b1[0] = (short)f2bf(WP[2][0]); b1[1] = (short)f2bf(WP[2][1]);        \
    b1[2] = (short)f2bf(WP[2][2]); b1[3] = (short)f2bf(WP[2][3]);        \
    b1[4] = (short)f2bf(WP[3][0]); b1[5] = (short)f2bf(WP[3][1]);        \
    b1[6] = (short)f2bf(WP[3][2]); b1[7] = (short)f2bf(WP[3][3]);        \
    _Pragma("unroll")                                                    \
    for (int mi = 0; mi < 8; ++mi) {                                     \
      short8 a0 = *(const short8*)&At[S][(mi * 16 + r) * BK + ((g ^ sw) * 8)]; \
      acc[mi] = __builtin_amdgcn_mfma_f32_16x16x32_bf16(a0, b0, acc[mi], 0, 0, 0); \
    }                                                                    \
    _Pragma("unroll")                                                    \
    for (int mi = 0; mi < 8; ++mi) {                                     \
      short8 a1 = *(const short8*)&At[S][(mi * 16 + r) * BK + (((4 + g) ^ sw) * 8)]; \
      acc[mi] = __builtin_amdgcn_mfma_f32_16x16x32_bf16(a1, b1, acc[mi], 0, 0, 0); \
    }                                                                    \
  }

// one pipeline step: wait tile T, barrier, prefetch tile T+2, compute tile T
#define K3STEP(T, WPc, Sc, WPn, Sn)                                      \
  {                                                                      \
    if ((T) < NT3 - 1) { asm volatile("s_waitcnt vmcnt(8)" ::: "memory"); } \
    else               { asm volatile("s_waitcnt vmcnt(0)" ::: "memory"); } \
    MEMF(); __builtin_amdgcn_s_barrier(); MEMF();                        \
    if ((T) + 2 < NT3) { WISSUE((T) + 2, WPn); MEMF(); AISSUE((T) + 2, Sn); MEMF(); } \
    COMPUTE(WPc, Sc);                                                    \
  }

  MEMF(); WISSUE(0, wp0); MEMF(); AISSUE(0, 0); MEMF();
  WISSUE(1, wp1); MEMF(); AISSUE(1, 1); MEMF();

  K3STEP(0,  wp0, 0, wp2, 2)
  K3STEP(1,  wp1, 1, wp0, 0)
  K3STEP(2,  wp2, 2, wp1, 1)
  K3STEP(3,  wp0, 0, wp2, 2)
  K3STEP(4,  wp1, 1, wp0, 0)
  K3STEP(5,  wp2, 2, wp1, 1)
  K3STEP(6,  wp0, 0, wp2, 2)
  K3STEP(7,  wp1, 1, wp0, 0)
  K3STEP(8,  wp2, 2, wp1, 1)
  K3STEP(9,  wp0, 0, wp2, 2)
  K3STEP(10, wp1, 1, wp0, 0)
  K3STEP(11, wp2, 2, wp1, 1)
  K3STEP(12, wp0, 0, wp2, 2)
  K3STEP(13, wp1, 1, wp0, 0)
  K3STEP(14, wp2, 2, wp1, 1)   // T+2 = 16 -> no issue
  K3STEP(15, wp0, 0, wp2, 2)   // T+2 = 17 -> no issue

#undef WISSUE
#undef AISSUE
#undef COMPUTE
#undef K3STEP

  // ---- epilogue: bias, store logits, wave-parallel softmax partials ----
  const int v = vb + wid * 16 + r;
  const bool vok = (v < VOCAB);
  float bias = bout[vok ? v : VOCAB - 1];
#pragma unroll
  for (int mi = 0; mi < 8; ++mi) {
#pragma unroll
    for (int rr = 0; rr < 4; ++rr) {
      float val = acc[mi][rr] + bias;
      int b = mi * 16 + g * 4 + rr;
      if (vok) out[(size_t)b * VOCAB + v] = val;
      float sv = vok ? val : -INFINITY;
      float m = sv;
      m = fmaxf(m, __shfl_xor(m, 1));
      m = fmaxf(m, __shfl_xor(m, 2));
      m = fmaxf(m, __shfl_xor(m, 4));
      m = fmaxf(m, __shfl_xor(m, 8));
      float ss = vok ? __expf(sv - m) : 0.f;
      ss += __shfl_xor(ss, 1);
      ss += __shfl_xor(ss, 2);
      ss += __shfl_xor(ss, 4);
      ss += __shfl_xor(ss, 8);
      if (r == 0) part[((size_t)blockIdx.x * 4 + wid) * 128 + b] = make_float2(m, ss);
    }
  }
}

// ---------------- K4: combine per-wave partials -> stat[b] ----------------
__global__ __launch_bounds__(256) void k4_combine(
    const float2* __restrict__ part, float* __restrict__ stat) {
  const int NP = NBLK3 * 4;   // 3144
  int b = blockIdx.x, t = threadIdx.x;
  float m = -INFINITY;
  for (int i = t; i < NP; i += 256) m = fmaxf(m, part[(size_t)i * 128 + b].x);
  __shared__ float red[256];
  red[t] = m; __syncthreads();
  for (int s = 128; s > 0; s >>= 1) {
    if (t < s) red[t] = fmaxf(red[t], red[t + s]);
    __syncthreads();
  }
  float M = red[0]; __syncthreads();
  float ssum = 0.f;
  for (int i = t; i < NP; i += 256) {
    float2 p = part[(size_t)i * 128 + b];
    ssum += p.y * __expf(p.x - M);
  }
  red[t] = ssum; __syncthreads();
  for (int s = 128; s > 0; s >>= 1) {
    if (t < s) red[t] += red[t + s];
    __syncthreads();
  }
  if (t == 0) stat[b] = M + logf(red[0]);
}

// ---------------- K5: out = logit - stat[b], float4 ----------------
__global__ __launch_bounds__(256) void k5_final(
    float* __restrict__ out, const float* __restrict__ stat) {
  const int total = BATCH * VOCAB;        // 6432896, divisible by 4
  int i4 = blockIdx.x * 256 + threadIdx.x;
  int base = i4 * 4;
  if (base >= total) return;
  float4 v = *(float4*)(out + base);
  int b0 = base / VOCAB, b3 = (base + 3) / VOCAB;
  if (b0 == b3) {
    float s = stat[b0];
    v.x -= s; v.y -= s; v.z -= s; v.w -= s;
  } else {
    v.x -= stat[base / VOCAB];
    v.y -= stat[(base + 1) / VOCAB];
    v.z -= stat[(base + 2) / VOCAB];
    v.w -= stat[(base + 3) / VOCAB];
  }
  *(float4*)(out + base) = v;
}

extern "C" void kernel_launch(void* const* d_in, const int* in_sizes, int n_in,
                              void* d_out, int out_size, void* d_ws, size_t ws_size,
                              hipStream_t stream) {
  const int*   ids   = (const int*)  d_in[0];
  const float* hprev = (const float*)d_in[1];
  // d_in[2] = encoder_output, unused by the reference
  const float* emb   = (const float*)d_in[3];
  const float* wih   = (const float*)d_in[4];
  const float* whh   = (const float*)d_in[5];
  const float* bih   = (const float*)d_in[6];
  const float* bhh   = (const float*)d_in[7];
  const float* Wout  = (const float*)d_in[8];
  const float* bout  = (const float*)d_in[9];
  float* out = (float*)d_out;
  char* ws = (char*)d_ws;

  // ws layout (bytes); max end ~12.01 MB. part/stat alias dead whhbf region.
  ushort_t* xbf   = (ushort_t*)(ws + 0);         // 128x320 bf16
  ushort_t* hbf   = (ushort_t*)(ws + 81920);     // 128x1024 bf16
  ushort_t* wihbf = (ushort_t*)(ws + 344064);    // 3072x320 bf16
  ushort_t* whhbf = (ushort_t*)(ws + 2310144);   // 3072x1024 bf16 (dead after k1)
  float*    gi    = (float*)(ws + 8601600);      // 128x3072 f32
  float*    gh    = (float*)(ws + 10174464);     // 128x3072 f32
  ushort_t* hnbf  = (ushort_t*)(ws + 11747328);  // 128x1024 bf16
  float2*   part  = (float2*)(ws + 2310144);     // 3144x128 float2 (aliases whhbf)
  float*    stat  = (float*)(ws + 5529600);      // 128 f32

  float* hnew_out = out + (size_t)BATCH * VOCAB;

  hipLaunchKernelGGL(k0_prep, dim3(6048), dim3(256), 0, stream,
                     ids, emb, hprev, wih, whh, xbf, hbf, wihbf, whhbf);
  hipLaunchKernelGGL(k1_gemm_gates, dim3(192, 2), dim3(64), 0, stream,
                     xbf, hbf, wihbf, whhbf, gi, gh);
  hipLaunchKernelGGL(k2_gates, dim3(512), dim3(256), 0, stream,
                     gi, gh, bih, bhh, hprev, hnew_out, hnbf);
  hipLaunchKernelGGL(k3_logits, dim3(NBLK3), dim3(256), 0, stream,
                     hnbf, Wout, bout, out, part);
  hipLaunchKernelGGL(k4_combine, dim3(128), dim3(256), 0, stream, part, stat);
  hipLaunchKernelGGL(k5_final, dim3((BATCH * VOCAB / 4 + 255) / 256), dim3(256), 0, stream,
                     out, stat);
}